// Round 1
// baseline (758.323 us; speedup 1.0000x reference)
//
#include <hip/hip_runtime.h>
#include <stdint.h>

#define B_SZ   8192
#define IN_DIM 512
#define HID    256
#define PROJ   128

typedef __attribute__((ext_vector_type(8))) short bf16x8;
typedef __attribute__((ext_vector_type(4))) float f32x4;

__device__ __forceinline__ unsigned short f2bf(float f) {
    union { float f; uint32_t u; } c; c.f = f;
    uint32_t u = c.u;
    uint32_t r = (u + 0x7fffu + ((u >> 16) & 1u)) >> 16;   // RNE
    return (unsigned short)r;
}

// ---------------- K0: convert W2, fused_text, W1 to bf16 ----------------
__global__ __launch_bounds__(256) void k0_convert(
        const float4* __restrict__ W2, const float4* __restrict__ ft,
        const float4* __restrict__ W1,
        ushort4* __restrict__ W2b, ushort4* __restrict__ ftb,
        ushort4* __restrict__ W1b) {
    const int nW2 = (PROJ * IN_DIM * HID) / 4;   // 4,194,304
    const int nft = (B_SZ * IN_DIM) / 4;         // 1,048,576
    const int nW1 = (HID * IN_DIM) / 4;          // 32,768
    const int total = nW2 + nft + nW1;
    int stride = gridDim.x * blockDim.x;
    for (int i = blockIdx.x * blockDim.x + threadIdx.x; i < total; i += stride) {
        const float4* s; ushort4* d; int j;
        if (i < nW2)            { s = W2; d = W2b; j = i; }
        else if (i < nW2 + nft) { s = ft; d = ftb; j = i - nW2; }
        else                    { s = W1; d = W1b; j = i - nW2 - nft; }
        float4 v = s[j];
        ushort4 o;
        o.x = f2bf(v.x); o.y = f2bf(v.y); o.z = f2bf(v.z); o.w = f2bf(v.w);
        d[j] = o;
    }
}

// ---------------- K1: h = relu(ft @ W1^T + b1), bf16 out ----------------
// wave: 64 samples x 64 hidden (4x4 tiles of 16x16), K=512 (16 mfma steps)
__global__ __launch_bounds__(256) void k1_hidden(
        const unsigned short* __restrict__ ftb,
        const unsigned short* __restrict__ W1b,
        const float* __restrict__ b1,
        unsigned short* __restrict__ hb) {
    const int lane = threadIdx.x & 63;
    const int wv   = threadIdx.x >> 6;    // nt-group 0..3
    const int l15  = lane & 15, q = lane >> 4;
    const int b0 = blockIdx.x * 64;
    const int n0 = wv * 64;

    f32x4 acc[4][4];
    const f32x4 z4 = {0.f, 0.f, 0.f, 0.f};
    #pragma unroll
    for (int mt = 0; mt < 4; ++mt)
        #pragma unroll
        for (int nt = 0; nt < 4; ++nt) acc[mt][nt] = z4;

    for (int kq = 0; kq < 16; ++kq) {
        const int koff = kq * 32 + q * 8;
        bf16x8 a[4], bb[4];
        #pragma unroll
        for (int mt = 0; mt < 4; ++mt)
            a[mt] = *(const bf16x8*)(ftb + (size_t)(b0 + mt*16 + l15) * IN_DIM + koff);
        #pragma unroll
        for (int nt = 0; nt < 4; ++nt)
            bb[nt] = *(const bf16x8*)(W1b + (size_t)(n0 + nt*16 + l15) * IN_DIM + koff);
        #pragma unroll
        for (int mt = 0; mt < 4; ++mt)
            #pragma unroll
            for (int nt = 0; nt < 4; ++nt)
                acc[mt][nt] = __builtin_amdgcn_mfma_f32_16x16x32_bf16(
                    a[mt], bb[nt], acc[mt][nt], 0, 0, 0);
    }
    #pragma unroll
    for (int nt = 0; nt < 4; ++nt) {
        float bias = b1[n0 + nt*16 + l15];
        #pragma unroll
        for (int mt = 0; mt < 4; ++mt)
            #pragma unroll
            for (int r = 0; r < 4; ++r) {
                float v = acc[mt][nt][r] + bias;
                v = fmaxf(v, 0.f);
                hb[(size_t)(b0 + mt*16 + q*4 + r) * HID + n0 + nt*16 + l15] = f2bf(v);
            }
    }
}

// ---------------- K3: out[b,p] = sum_i x*(sum_k h*W2 + b2) ----------------
// wave: 64 samples x 4 p's. Per (p, khalf): A-frags (h) register-resident,
// B-frags (W2 rows, native layout) double-buffered from global (L1/L2/L3).
// Epilogue folds x (fp32) and b2 per 16-pi tile. No LDS, no barriers.
__global__ __launch_bounds__(256, 2) void k3_main(
        const unsigned short* __restrict__ W2b,
        const unsigned short* __restrict__ hb,
        const float* __restrict__ x,
        const float* __restrict__ b2,
        float* __restrict__ out) {
    const int lane = threadIdx.x & 63;
    const int wv   = threadIdx.x >> 6;
    const int l15  = lane & 15, q = lane >> 4;
    const int wid  = blockIdx.x * 4 + wv;      // 0..4095; consecutive = same p-group
    const int b0   = (wid & 127) * 64;
    const int p0   = (wid >> 7) * 4;
    const f32x4 z4 = {0.f, 0.f, 0.f, 0.f};

    #pragma unroll 1
    for (int pp = 0; pp < 4; ++pp) {
        const int p = p0 + pp;
        float oacc[4][4];
        #pragma unroll
        for (int mt = 0; mt < 4; ++mt)
            #pragma unroll
            for (int r = 0; r < 4; ++r) oacc[mt][r] = 0.f;

        #pragma unroll
        for (int kh = 0; kh < 2; ++kh) {
            // A-frags: h[b0.., kh*128 .. +128)  (64 VGPRs, reloaded per (p,kh) from L1)
            bf16x8 afr[4][4];
            #pragma unroll
            for (int mt = 0; mt < 4; ++mt) {
                const unsigned short* hrow =
                    hb + (size_t)(b0 + mt*16 + l15) * HID + kh*128 + q*8;
                #pragma unroll
                for (int kq = 0; kq < 4; ++kq)
                    afr[mt][kq] = *(const bf16x8*)(hrow + kq*32);
            }
            const unsigned short* wbase =
                W2b + ((size_t)p * 512 + l15) * HID + kh*128 + q*8;

            bf16x8 bufA[4], bufB[4];
            #pragma unroll
            for (int kq = 0; kq < 4; ++kq)
                bufA[kq] = *(const bf16x8*)(wbase + kq*32);

            auto step = [&](int it, const bf16x8* bc, bf16x8* bn) {
                const int nit = (it < 31) ? it + 1 : 31;
                // prefetch next B-frags
                #pragma unroll
                for (int kq = 0; kq < 4; ++kq)
                    bn[kq] = *(const bf16x8*)(wbase + (size_t)nit*16*HID + kq*32);
                // x values for epilogue (issue early; 64B-coalesced per 16-lane group)
                float xv[4][4];
                #pragma unroll
                for (int mt = 0; mt < 4; ++mt)
                    #pragma unroll
                    for (int r = 0; r < 4; ++r)
                        xv[mt][r] = x[(size_t)(b0 + mt*16 + q*4 + r) * IN_DIM + it*16 + l15];
                float b2v = 0.f;
                if (kh == 0) b2v = b2[(size_t)p * 512 + it*16 + l15];

                f32x4 D[4];
                #pragma unroll
                for (int mt = 0; mt < 4; ++mt)
                    D[mt] = __builtin_amdgcn_mfma_f32_16x16x32_bf16(afr[mt][0], bc[0], z4, 0, 0, 0);
                #pragma unroll
                for (int kq = 1; kq < 4; ++kq)
                    #pragma unroll
                    for (int mt = 0; mt < 4; ++mt)
                        D[mt] = __builtin_amdgcn_mfma_f32_16x16x32_bf16(afr[mt][kq], bc[kq], D[mt], 0, 0, 0);
                #pragma unroll
                for (int mt = 0; mt < 4; ++mt)
                    #pragma unroll
                    for (int r = 0; r < 4; ++r)
                        oacc[mt][r] += (D[mt][r] + b2v) * xv[mt][r];
            };

            #pragma unroll 1
            for (int it2 = 0; it2 < 16; ++it2) {
                step(2*it2,     bufA, bufB);
                step(2*it2 + 1, bufB, bufA);
            }
        }
        // reduce over the 16 i-lanes of each group, lane 0 stores
        #pragma unroll
        for (int mt = 0; mt < 4; ++mt)
            #pragma unroll
            for (int r = 0; r < 4; ++r) {
                float v = oacc[mt][r];
                v += __shfl_xor(v, 1, 16);
                v += __shfl_xor(v, 2, 16);
                v += __shfl_xor(v, 4, 16);
                v += __shfl_xor(v, 8, 16);
                if (l15 == 0)
                    out[(size_t)(b0 + mt*16 + q*4 + r) * PROJ + p] = v;
            }
    }
}

extern "C" void kernel_launch(void* const* d_in, const int* in_sizes, int n_in,
                              void* d_out, int out_size, void* d_ws, size_t ws_size,
                              hipStream_t stream) {
    const float* ft = (const float*)d_in[0];
    const float* x  = (const float*)d_in[1];
    const float* W1 = (const float*)d_in[2];
    const float* b1 = (const float*)d_in[3];
    const float* W2 = (const float*)d_in[4];
    const float* b2 = (const float*)d_in[5];
    float* out = (float*)d_out;

    char* ws = (char*)d_ws;
    unsigned short* W2b = (unsigned short*)(ws);             // 33,554,432 B
    unsigned short* ftb = (unsigned short*)(ws + 33554432);  //  8,388,608 B
    unsigned short* W1b = (unsigned short*)(ws + 41943040);  //    262,144 B
    unsigned short* hb  = (unsigned short*)(ws + 42205184);  //  4,194,304 B

    hipLaunchKernelGGL(k0_convert, dim3(2048), dim3(256), 0, stream,
        (const float4*)W2, (const float4*)ft, (const float4*)W1,
        (ushort4*)W2b, (ushort4*)ftb, (ushort4*)W1b);
    hipLaunchKernelGGL(k1_hidden, dim3(128), dim3(256), 0, stream, ftb, W1b, b1, hb);
    hipLaunchKernelGGL(k3_main, dim3(1024), dim3(256), 0, stream, W2b, hb, x, b2, out);
}